// Round 1
// baseline (560.003 us; speedup 1.0000x reference)
//
#include <hip/hip_runtime.h>

#define DD 64

__global__ void deg_init_k(float* __restrict__ deg, int N) {
    int i = blockIdx.x * blockDim.x + threadIdx.x;
    if (i < N) deg[i] = 1.0f;  // self-loop
}

__global__ void deg_accum_k(const int* __restrict__ dst, float* __restrict__ deg, int E) {
    int e = blockIdx.x * blockDim.x + threadIdx.x;
    if (e < E) atomicAdd(&deg[dst[e]], 1.0f);
}

__global__ void dinv_k(const float* __restrict__ deg, float* __restrict__ dinv, int N) {
    int i = blockIdx.x * blockDim.x + threadIdx.x;
    if (i < N) dinv[i] = rsqrtf(deg[i]);  // deg >= 1 always (self-loops)
}

// x = z @ W^T : x[n][d] = sum_k z[n][k] * W[d][k]
// 256 threads = 4 rows/block; lane d computes one output column.
// W^T staged in LDS padded [64][65]: writes (k varies per-lane) stride-65 -> conflict-free;
// reads Wt[k][lane] consecutive -> conflict-free.
__global__ void gemm_zwt_k(const float* __restrict__ z, const float* __restrict__ W,
                           float* __restrict__ x, int N) {
    __shared__ float Wt[DD][DD + 1];
    int tid = threadIdx.x;
    #pragma unroll
    for (int i = tid; i < DD * DD; i += 256) {
        int d = i >> 6, k = i & 63;
        Wt[k][d] = W[i];  // coalesced global read
    }
    __syncthreads();
    int lane = tid & 63;
    int row = blockIdx.x * 4 + (tid >> 6);
    if (row < N) {
        float zv = z[(size_t)row * DD + lane];
        float acc = 0.0f;
        #pragma unroll
        for (int k = 0; k < DD; ++k) {
            acc = fmaf(__shfl(zv, k, 64), Wt[k][lane], acc);
        }
        x[(size_t)row * DD + lane] = acc;
    }
}

// out[n][d] = x[n][d] * dinv[n]^2 + b[d]   (self-loop message + bias)
__global__ void init_out_k(const float* __restrict__ x, const float* __restrict__ dinv,
                           const float* __restrict__ b, float* __restrict__ out, int n4) {
    int i = blockIdx.x * blockDim.x + threadIdx.x;  // over N*16 float4s
    if (i < n4) {
        int n = i >> 4;
        int j = i & 15;
        float s = dinv[n];
        s = s * s;
        float4 xv = reinterpret_cast<const float4*>(x)[i];
        float4 bv = reinterpret_cast<const float4*>(b)[j];
        float4 o;
        o.x = fmaf(xv.x, s, bv.x);
        o.y = fmaf(xv.y, s, bv.y);
        o.z = fmaf(xv.z, s, bv.z);
        o.w = fmaf(xv.w, s, bv.w);
        reinterpret_cast<float4*>(out)[i] = o;
    }
}

// one wave per edge: lane d does out[dst*64+d] += x[src*64+d] * dinv[src]*dinv[dst]
__global__ void scatter_k(const float* __restrict__ x, const float* __restrict__ dinv,
                          const int* __restrict__ src, const int* __restrict__ dst,
                          float* __restrict__ out, int E) {
    long long gid = (long long)blockIdx.x * blockDim.x + threadIdx.x;
    int e = (int)(gid >> 6);
    int d = (int)(gid & 63);
    if (e < E) {
        int s = src[e];   // same addr across wave -> broadcast load
        int t = dst[e];
        float norm = dinv[s] * dinv[t];
        float v = x[(size_t)s * DD + d] * norm;  // coalesced 256B row read
        atomicAdd(&out[(size_t)t * DD + d], v);
    }
}

__global__ void relu_k(float* __restrict__ out, int n4) {
    int i = blockIdx.x * blockDim.x + threadIdx.x;
    if (i < n4) {
        float4 v = reinterpret_cast<float4*>(out)[i];
        v.x = fmaxf(v.x, 0.0f);
        v.y = fmaxf(v.y, 0.0f);
        v.z = fmaxf(v.z, 0.0f);
        v.w = fmaxf(v.w, 0.0f);
        reinterpret_cast<float4*>(out)[i] = v;
    }
}

extern "C" void kernel_launch(void* const* d_in, const int* in_sizes, int n_in,
                              void* d_out, int out_size, void* d_ws, size_t ws_size,
                              hipStream_t stream) {
    const float* z = (const float*)d_in[0];
    const int* ei  = (const int*)d_in[1];
    const float* W = (const float*)d_in[2];
    const float* b = (const float*)d_in[3];
    float* out = (float*)d_out;

    const int N = in_sizes[0] / DD;
    const int E = in_sizes[1] / 2;
    const int* src = ei;       // ei[0]
    const int* dst = ei + E;   // ei[1]

    float* ws   = (float*)d_ws;
    float* deg  = ws;            // N floats
    float* dinv = ws + N;        // N floats
    float* x    = ws + 2 * N;    // N*64 floats

    deg_init_k<<<(N + 255) / 256, 256, 0, stream>>>(deg, N);
    deg_accum_k<<<(E + 255) / 256, 256, 0, stream>>>(dst, deg, E);
    dinv_k<<<(N + 255) / 256, 256, 0, stream>>>(deg, dinv, N);
    gemm_zwt_k<<<(N + 3) / 4, 256, 0, stream>>>(z, W, x, N);

    int n4 = N * (DD / 4);
    init_out_k<<<(n4 + 255) / 256, 256, 0, stream>>>(x, dinv, b, out, n4);

    long long total = (long long)E * 64;
    int blocks = (int)((total + 255) / 256);
    scatter_k<<<blocks, 256, 0, stream>>>(x, dinv, src, dst, out, E);

    relu_k<<<(n4 + 255) / 256, 256, 0, stream>>>(out, n4);
}

// Round 2
// 495.963 us; speedup vs baseline: 1.1291x; 1.1291x over previous
//
#include <hip/hip_runtime.h>

#define DD 64

// ---------------- common ----------------

__global__ void zero_int_k(int* __restrict__ p, int n) {
    int i = blockIdx.x * blockDim.x + threadIdx.x;
    if (i < n) p[i] = 0;
}

__global__ void hist_k(const int* __restrict__ dst, int* __restrict__ cnt, int E) {
    int e = blockIdx.x * blockDim.x + threadIdx.x;
    if (e < E) atomicAdd(&cnt[dst[e]], 1);
}

__global__ void dinv_k(const int* __restrict__ cnt, float* __restrict__ dinv, int N) {
    int i = blockIdx.x * blockDim.x + threadIdx.x;
    if (i < N) dinv[i] = rsqrtf((float)(1 + cnt[i]));  // deg = 1 + in-degree (self-loop)
}

// x = z @ W^T : x[n][d] = sum_k z[n][k] * W[d][k]
__global__ void gemm_zwt_k(const float* __restrict__ z, const float* __restrict__ W,
                           float* __restrict__ x, int N) {
    __shared__ float Wt[DD][DD + 1];
    int tid = threadIdx.x;
    #pragma unroll
    for (int i = tid; i < DD * DD; i += 256) {
        int d = i >> 6, k = i & 63;
        Wt[k][d] = W[i];
    }
    __syncthreads();
    int lane = tid & 63;
    int row = blockIdx.x * 4 + (tid >> 6);
    if (row < N) {
        float zv = z[(size_t)row * DD + lane];
        float acc = 0.0f;
        #pragma unroll
        for (int k = 0; k < DD; ++k) {
            acc = fmaf(__shfl(zv, k, 64), Wt[k][lane], acc);
        }
        x[(size_t)row * DD + lane] = acc;
    }
}

// ---------------- CSR build (counting sort by dst) ----------------

// per-block (256-wide) exclusive scan of cnt -> rs, block total -> bsum
__global__ void scan1_k(const int* __restrict__ cnt, int* __restrict__ rs,
                        int* __restrict__ bsum, int N) {
    __shared__ int sm[256];
    int tid = threadIdx.x;
    int i = blockIdx.x * 256 + tid;
    int v = (i < N) ? cnt[i] : 0;
    sm[tid] = v;
    __syncthreads();
    #pragma unroll
    for (int off = 1; off < 256; off <<= 1) {
        int t = (tid >= off) ? sm[tid - off] : 0;
        __syncthreads();
        sm[tid] += t;
        __syncthreads();
    }
    if (i < N) rs[i] = sm[tid] - v;  // exclusive
    if (tid == 255) bsum[blockIdx.x] = sm[255];
}

// serial scan of block sums (nb ~ 391, trivial)
__global__ void scan2_k(int* __restrict__ bsum, int nb) {
    if (threadIdx.x == 0 && blockIdx.x == 0) {
        int run = 0;
        for (int i = 0; i < nb; ++i) {
            int v = bsum[i];
            bsum[i] = run;
            run += v;
        }
    }
}

// add block offsets; duplicate into fill_ptr for the counting-sort pass
__global__ void scan3_k(int* __restrict__ rs, const int* __restrict__ bsum,
                        int* __restrict__ fptr, int N) {
    int i = blockIdx.x * blockDim.x + threadIdx.x;
    if (i < N) {
        int v = rs[i] + bsum[i >> 8];
        rs[i] = v;
        fptr[i] = v;
    }
}

__global__ void fill_k(const int* __restrict__ src, const int* __restrict__ dst,
                       int* __restrict__ fptr, int* __restrict__ ss, int E) {
    int e = blockIdx.x * blockDim.x + threadIdx.x;
    if (e < E) {
        int t = dst[e];
        int p = atomicAdd(&fptr[t], 1);
        ss[p] = src[e];
    }
}

// ---------------- fused pull-gather + self-loop + bias + ReLU ----------------
// one wave per node; lane d owns out[n][d].
// out[n] = relu( dinv[n] * ( x[n]*dinv[n] + sum_{s in N(n)} x[s]*dinv[s] ) + b )
__global__ void gather_k(const float* __restrict__ x, const float* __restrict__ dinv,
                         const int* __restrict__ rs, const int* __restrict__ cnt,
                         const int* __restrict__ ss, const float* __restrict__ b,
                         float* __restrict__ out, int N) {
    int tid = threadIdx.x;
    int lane = tid & 63;
    int n = blockIdx.x * 4 + (tid >> 6);
    if (n >= N) return;
    float dn = dinv[n];
    float acc = x[(size_t)n * DD + lane] * dn;  // self-loop message
    int beg = rs[n];
    int num = cnt[n];
    for (int j = 0; j < num; ++j) {
        int s = ss[beg + j];                     // wave-uniform broadcast load
        acc = fmaf(x[(size_t)s * DD + lane], dinv[s], acc);  // coalesced 256B row
    }
    float o = fmaf(acc, dn, b[lane]);
    out[(size_t)n * DD + lane] = fmaxf(o, 0.0f);
}

// ---------------- fallback (atomic scatter) if ws too small ----------------

__global__ void init_out_k(const float* __restrict__ x, const float* __restrict__ dinv,
                           const float* __restrict__ b, float* __restrict__ out, int n4) {
    int i = blockIdx.x * blockDim.x + threadIdx.x;
    if (i < n4) {
        int n = i >> 4;
        int j = i & 15;
        float s = dinv[n];
        s = s * s;
        float4 xv = reinterpret_cast<const float4*>(x)[i];
        float4 bv = reinterpret_cast<const float4*>(b)[j];
        float4 o;
        o.x = fmaf(xv.x, s, bv.x);
        o.y = fmaf(xv.y, s, bv.y);
        o.z = fmaf(xv.z, s, bv.z);
        o.w = fmaf(xv.w, s, bv.w);
        reinterpret_cast<float4*>(out)[i] = o;
    }
}

__global__ void scatter_k(const float* __restrict__ x, const float* __restrict__ dinv,
                          const int* __restrict__ src, const int* __restrict__ dst,
                          float* __restrict__ out, int E) {
    long long gid = (long long)blockIdx.x * blockDim.x + threadIdx.x;
    int e = (int)(gid >> 6);
    int d = (int)(gid & 63);
    if (e < E) {
        int s = src[e];
        int t = dst[e];
        float norm = dinv[s] * dinv[t];
        float v = x[(size_t)s * DD + d] * norm;
        atomicAdd(&out[(size_t)t * DD + d], v);
    }
}

__global__ void relu_k(float* __restrict__ out, int n4) {
    int i = blockIdx.x * blockDim.x + threadIdx.x;
    if (i < n4) {
        float4 v = reinterpret_cast<float4*>(out)[i];
        v.x = fmaxf(v.x, 0.0f);
        v.y = fmaxf(v.y, 0.0f);
        v.z = fmaxf(v.z, 0.0f);
        v.w = fmaxf(v.w, 0.0f);
        reinterpret_cast<float4*>(out)[i] = v;
    }
}

// ---------------- launch ----------------

extern "C" void kernel_launch(void* const* d_in, const int* in_sizes, int n_in,
                              void* d_out, int out_size, void* d_ws, size_t ws_size,
                              hipStream_t stream) {
    const float* z = (const float*)d_in[0];
    const int* ei  = (const int*)d_in[1];
    const float* W = (const float*)d_in[2];
    const float* b = (const float*)d_in[3];
    float* out = (float*)d_out;

    const int N = in_sizes[0] / DD;
    const int E = in_sizes[1] / 2;
    const int* src = ei;
    const int* dst = ei + E;

    const int nb = (N + 255) / 256;  // scan blocks

    // workspace layout
    float* ws   = (float*)d_ws;
    float* x    = ws;                       // 64N floats
    float* dinv = ws + (size_t)64 * N;      // N floats
    int*   cnt  = (int*)(dinv + N);         // N ints
    int*   rs   = cnt + N;                  // N ints
    int*   fptr = rs + N;                   // N ints
    int*   bsum = fptr + N;                 // nb ints
    int*   ss   = bsum + nb;                // E ints

    size_t need_new = sizeof(int) * ((size_t)68 * N + nb + E);

    // common prologue
    zero_int_k<<<(N + 255) / 256, 256, 0, stream>>>(cnt, N);
    hist_k<<<(E + 255) / 256, 256, 0, stream>>>(dst, cnt, E);
    dinv_k<<<(N + 255) / 256, 256, 0, stream>>>(cnt, dinv, N);
    gemm_zwt_k<<<(N + 3) / 4, 256, 0, stream>>>(z, W, x, N);

    if (ws_size >= need_new) {
        // CSR build
        scan1_k<<<nb, 256, 0, stream>>>(cnt, rs, bsum, N);
        scan2_k<<<1, 64, 0, stream>>>(bsum, nb);
        scan3_k<<<(N + 255) / 256, 256, 0, stream>>>(rs, bsum, fptr, N);
        fill_k<<<(E + 255) / 256, 256, 0, stream>>>(src, dst, fptr, ss, E);
        // fused pull gather
        gather_k<<<(N + 3) / 4, 256, 0, stream>>>(x, dinv, rs, cnt, ss, b, out, N);
    } else {
        // fallback: atomic scatter path
        int n4 = N * (DD / 4);
        init_out_k<<<(n4 + 255) / 256, 256, 0, stream>>>(x, dinv, b, out, n4);
        long long total = (long long)E * 64;
        int blocks = (int)((total + 255) / 256);
        scatter_k<<<blocks, 256, 0, stream>>>(x, dinv, src, dst, out, E);
        relu_k<<<(n4 + 255) / 256, 256, 0, stream>>>(out, n4);
    }
}

// Round 3
// 291.841 us; speedup vs baseline: 1.9189x; 1.6994x over previous
//
#include <hip/hip_runtime.h>

#define DD 64

__device__ __forceinline__ float4 f4add(float4 a, float4 b) {
    return make_float4(a.x + b.x, a.y + b.y, a.z + b.z, a.w + b.w);
}

// ---------------- CSR infra ----------------

__global__ void zero_int_k(int* __restrict__ p, int n) {
    int i = blockIdx.x * blockDim.x + threadIdx.x;
    if (i < n) p[i] = 0;
}

__global__ void hist_k(const int* __restrict__ dst, int* __restrict__ cnt, int E) {
    int e = blockIdx.x * blockDim.x + threadIdx.x;
    if (e < E) atomicAdd(&cnt[dst[e]], 1);
}

// per-block exclusive scan of cnt -> rs, block total -> bsum; fused dinv = rsqrt(1+cnt)
__global__ void scan1_k(const int* __restrict__ cnt, float* __restrict__ dinv,
                        int* __restrict__ rs, int* __restrict__ bsum, int N) {
    __shared__ int sm[256];
    int tid = threadIdx.x;
    int i = blockIdx.x * 256 + tid;
    int v = (i < N) ? cnt[i] : 0;
    sm[tid] = v;
    __syncthreads();
    #pragma unroll
    for (int off = 1; off < 256; off <<= 1) {
        int t = (tid >= off) ? sm[tid - off] : 0;
        __syncthreads();
        sm[tid] += t;
        __syncthreads();
    }
    if (i < N) {
        rs[i] = sm[tid] - v;                    // exclusive
        dinv[i] = rsqrtf((float)(1 + v));       // deg = 1 + in-degree
    }
    if (tid == 255) bsum[blockIdx.x] = sm[255];
}

// wave-parallel scan of block sums (nb ~ 391): 64-lane shfl scan, chunked
__global__ void scan2_k(int* __restrict__ bsum, int nb) {
    int lane = threadIdx.x;  // one 64-thread block
    int run = 0;
    for (int base = 0; base < nb; base += 64) {
        int i = base + lane;
        int orig = (i < nb) ? bsum[i] : 0;
        int v = orig;
        #pragma unroll
        for (int off = 1; off < 64; off <<= 1) {
            int t = __shfl_up(v, off, 64);
            if (lane >= off) v += t;
        }
        if (i < nb) bsum[i] = run + v - orig;   // exclusive w/ running offset
        run += __shfl(v, 63, 64);
    }
}

__global__ void scan3_k(int* __restrict__ rs, const int* __restrict__ bsum,
                        int* __restrict__ fptr, int N) {
    int i = blockIdx.x * blockDim.x + threadIdx.x;
    if (i < N) {
        int v = rs[i] + bsum[i >> 8];
        rs[i] = v;
        fptr[i] = v;
    }
}

__global__ void fill_k(const int* __restrict__ src, const int* __restrict__ dst,
                       int* __restrict__ fptr, int* __restrict__ ss, int E) {
    int e = blockIdx.x * blockDim.x + threadIdx.x;
    if (e < E) {
        int t = dst[e];
        int p = atomicAdd(&fptr[t], 1);
        ss[p] = src[e];
    }
}

// ---------------- y = (z @ W^T) * dinv[n] ----------------
// 256 thr: 16 rows x 16 colgroups(float4). W^T in LDS [64][68] (16B-aligned rows).
__global__ void gemm_k(const float* __restrict__ z, const float* __restrict__ W,
                       const float* __restrict__ dinv, float* __restrict__ y, int N) {
    __shared__ float Wt[64 * 68];   // Wt[k*68 + d] = W[d*64 + k]
    __shared__ float zt[16 * 68];
    int tid = threadIdx.x;
    for (int i = tid; i < DD * DD; i += 256) {
        int d = i >> 6, k = i & 63;
        Wt[k * 68 + d] = W[i];      // coalesced global read, transposed LDS write
    }
    {
        int zr = blockIdx.x * 16 + (tid >> 4);
        float4 v = (zr < N) ? reinterpret_cast<const float4*>(z)[(size_t)zr * 16 + (tid & 15)]
                            : make_float4(0.f, 0.f, 0.f, 0.f);
        *reinterpret_cast<float4*>(&zt[(tid >> 4) * 68 + (tid & 15) * 4]) = v;
    }
    __syncthreads();
    int r = tid >> 4;
    int c = tid & 15;
    int row = blockIdx.x * 16 + r;
    float4 acc = make_float4(0.f, 0.f, 0.f, 0.f);
    #pragma unroll
    for (int k = 0; k < DD; ++k) {
        float zv = zt[r * 68 + k];                                      // broadcast
        float4 w = *reinterpret_cast<const float4*>(&Wt[k * 68 + c * 4]); // b128, conflict-free
        acc.x = fmaf(zv, w.x, acc.x);
        acc.y = fmaf(zv, w.y, acc.y);
        acc.z = fmaf(zv, w.z, acc.z);
        acc.w = fmaf(zv, w.w, acc.w);
    }
    if (row < N) {
        float s = dinv[row];
        acc.x *= s; acc.y *= s; acc.z *= s; acc.w *= s;
        reinterpret_cast<float4*>(y)[(size_t)row * 16 + c] = acc;
    }
}

// ---------------- fused pull-gather + self + bias + ReLU ----------------
// wave per node; 8 edge-groups x 8 lanes; lane owns 8 cols (2 x float4).
// out[n] = relu( dinv[n] * ( y[n] + sum_{s in N(n)} y[s] ) + b )
__global__ void gather_k(const float4* __restrict__ y4, const float* __restrict__ dinv,
                         const int* __restrict__ rs, const int* __restrict__ cnt,
                         const int* __restrict__ ss, const float4* __restrict__ b4,
                         float4* __restrict__ out4, int N) {
    int tid = threadIdx.x;
    int lane = tid & 63;
    int n = blockIdx.x * 4 + (tid >> 6);
    if (n >= N) return;
    int g = lane >> 3;          // edge group 0..7
    int c = lane & 7;           // col block: float4 idx 2c, 2c+1
    int beg = rs[n];
    int num = cnt[n];
    float4 a0 = make_float4(0.f, 0.f, 0.f, 0.f);
    float4 a1 = a0;
    if (g == 0) {               // self-loop message (y already dinv-scaled)
        a0 = y4[(size_t)n * 16 + 2 * c];
        a1 = y4[(size_t)n * 16 + 2 * c + 1];
    }
    for (int j = g; j < num; j += 8) {
        int s = ss[beg + j];                    // uniform within 8-lane group
        size_t p = (size_t)s * 16 + 2 * c;
        float4 v0 = y4[p];                      // 8 rows x 2x128b in flight per wave
        float4 v1 = y4[p + 1];
        a0 = f4add(a0, v0);
        a1 = f4add(a1, v1);
    }
    // reduce across the 8 groups (same c): masks 8,16,32
    #pragma unroll
    for (int m = 8; m <= 32; m <<= 1) {
        a0.x += __shfl_xor(a0.x, m, 64);
        a0.y += __shfl_xor(a0.y, m, 64);
        a0.z += __shfl_xor(a0.z, m, 64);
        a0.w += __shfl_xor(a0.w, m, 64);
        a1.x += __shfl_xor(a1.x, m, 64);
        a1.y += __shfl_xor(a1.y, m, 64);
        a1.z += __shfl_xor(a1.z, m, 64);
        a1.w += __shfl_xor(a1.w, m, 64);
    }
    if (g == 0) {
        float dn = dinv[n];
        float4 bb0 = b4[2 * c];
        float4 bb1 = b4[2 * c + 1];
        float4 o0, o1;
        o0.x = fmaxf(fmaf(a0.x, dn, bb0.x), 0.f);
        o0.y = fmaxf(fmaf(a0.y, dn, bb0.y), 0.f);
        o0.z = fmaxf(fmaf(a0.z, dn, bb0.z), 0.f);
        o0.w = fmaxf(fmaf(a0.w, dn, bb0.w), 0.f);
        o1.x = fmaxf(fmaf(a1.x, dn, bb1.x), 0.f);
        o1.y = fmaxf(fmaf(a1.y, dn, bb1.y), 0.f);
        o1.z = fmaxf(fmaf(a1.z, dn, bb1.z), 0.f);
        o1.w = fmaxf(fmaf(a1.w, dn, bb1.w), 0.f);
        out4[(size_t)n * 16 + 2 * c] = o0;
        out4[(size_t)n * 16 + 2 * c + 1] = o1;
    }
}

// ---------------- launch ----------------

extern "C" void kernel_launch(void* const* d_in, const int* in_sizes, int n_in,
                              void* d_out, int out_size, void* d_ws, size_t ws_size,
                              hipStream_t stream) {
    const float* z = (const float*)d_in[0];
    const int* ei  = (const int*)d_in[1];
    const float* W = (const float*)d_in[2];
    const float* b = (const float*)d_in[3];
    float* out = (float*)d_out;

    const int N = in_sizes[0] / DD;
    const int E = in_sizes[1] / 2;
    const int* src = ei;
    const int* dst = ei + E;

    const int nb = (N + 255) / 256;

    // workspace layout
    float* ws   = (float*)d_ws;
    float* y    = ws;                       // 64N floats
    float* dinv = ws + (size_t)64 * N;      // N
    int*   cnt  = (int*)(dinv + N);         // N
    int*   rs   = cnt + N;                  // N
    int*   fptr = rs + N;                   // N
    int*   bsum = fptr + N;                 // nb
    int*   ss   = bsum + nb;                // E

    zero_int_k<<<(N + 255) / 256, 256, 0, stream>>>(cnt, N);
    hist_k<<<(E + 255) / 256, 256, 0, stream>>>(dst, cnt, E);
    scan1_k<<<nb, 256, 0, stream>>>(cnt, dinv, rs, bsum, N);
    scan2_k<<<1, 64, 0, stream>>>(bsum, nb);
    scan3_k<<<(N + 255) / 256, 256, 0, stream>>>(rs, bsum, fptr, N);
    fill_k<<<(E + 255) / 256, 256, 0, stream>>>(src, dst, fptr, ss, E);
    gemm_k<<<(N + 15) / 16, 256, 0, stream>>>(z, W, dinv, y, N);
    gather_k<<<(N + 3) / 4, 256, 0, stream>>>((const float4*)y, dinv, rs, cnt, ss,
                                              (const float4*)b, (float4*)out, N);
}

// Round 4
// 246.795 us; speedup vs baseline: 2.2691x; 1.1825x over previous
//
#include <hip/hip_runtime.h>

#define DD 64
#define BKT_SHIFT 7            // 128 nodes per bucket
#define TILE 4096              // edges per partition block
#define MAXBK 1024             // LDS arrays sized for NBK <= 1024

__device__ __forceinline__ float4 f4add(float4 a, float4 b) {
    return make_float4(a.x + b.x, a.y + b.y, a.z + b.z, a.w + b.w);
}

// ---------------- CSR infra ----------------

__global__ void zero_int_k(int* __restrict__ p, int n) {
    int i = blockIdx.x * blockDim.x + threadIdx.x;
    if (i < n) p[i] = 0;
}

__global__ void hist_k(const int* __restrict__ dst, int* __restrict__ cnt, int E) {
    int e = blockIdx.x * blockDim.x + threadIdx.x;
    if (e < E) atomicAdd(&cnt[dst[e]], 1);
}

// per-block exclusive scan of cnt -> rs, block total -> bsum; fused dinv = rsqrt(1+cnt)
__global__ void scan1_k(const int* __restrict__ cnt, float* __restrict__ dinv,
                        int* __restrict__ rs, int* __restrict__ bsum, int N) {
    __shared__ int sm[256];
    int tid = threadIdx.x;
    int i = blockIdx.x * 256 + tid;
    int v = (i < N) ? cnt[i] : 0;
    sm[tid] = v;
    __syncthreads();
    #pragma unroll
    for (int off = 1; off < 256; off <<= 1) {
        int t = (tid >= off) ? sm[tid - off] : 0;
        __syncthreads();
        sm[tid] += t;
        __syncthreads();
    }
    if (i < N) {
        rs[i] = sm[tid] - v;
        dinv[i] = rsqrtf((float)(1 + v));
    }
    if (tid == 255) bsum[blockIdx.x] = sm[255];
}

// wave-parallel chunked scan of block sums
__global__ void scan2_k(int* __restrict__ bsum, int nb) {
    int lane = threadIdx.x;
    int run = 0;
    for (int base = 0; base < nb; base += 64) {
        int i = base + lane;
        int orig = (i < nb) ? bsum[i] : 0;
        int v = orig;
        #pragma unroll
        for (int off = 1; off < 64; off <<= 1) {
            int t = __shfl_up(v, off, 64);
            if (lane >= off) v += t;
        }
        if (i < nb) bsum[i] = run + v - orig;
        run += __shfl(v, 63, 64);
    }
}

// finalize rs, copy to fptr, init per-bucket cursors bcur[k] = rs[k<<BKT_SHIFT]
__global__ void scan3_k(int* __restrict__ rs, const int* __restrict__ bsum,
                        int* __restrict__ fptr, int* __restrict__ bcur, int N) {
    int i = blockIdx.x * blockDim.x + threadIdx.x;
    if (i < N) {
        int v = rs[i] + bsum[i >> 8];
        rs[i] = v;
        fptr[i] = v;
        if ((i & ((1 << BKT_SHIFT) - 1)) == 0) bcur[i >> BKT_SHIFT] = v;
    }
}

// ---------------- bucketed partition: edges -> bp grouped by dst bucket ----------------
__global__ __launch_bounds__(256) void part_k(const int* __restrict__ src,
                                              const int* __restrict__ dst,
                                              int* __restrict__ bcur,
                                              int2* __restrict__ bp,
                                              int E, int NBK) {
    __shared__ int hist[MAXBK];     // counts, then reused as staging cursor
    __shared__ int scanb[MAXBK];    // exclusive scan (local)
    __shared__ int gbase[MAXBK];    // reserved global base per bucket
    __shared__ int2 stage[TILE];    // 32 KB reordered tile

    int tid = threadIdx.x;
    int tbase = blockIdx.x * TILE;
    int n = E - tbase;
    if (n > TILE) n = TILE;

    for (int i = tid; i < NBK; i += 256) hist[i] = 0;
    __syncthreads();

    // load edges (static-indexed regs), count buckets
    int myS[TILE / 256], myD[TILE / 256];
    #pragma unroll
    for (int e = 0; e < TILE / 256; ++e) {
        int i = tid + e * 256;
        myS[e] = 0; myD[e] = -1;
        if (i < n) {
            myS[e] = src[tbase + i];
            myD[e] = dst[tbase + i];
            atomicAdd(&hist[myD[e] >> BKT_SHIFT], 1);
        }
    }
    __syncthreads();

    // one-wave chunked exclusive scan of hist -> scanb
    if (tid < 64) {
        int run = 0;
        for (int base = 0; base < NBK; base += 64) {
            int i = base + tid;
            int orig = (i < NBK) ? hist[i] : 0;
            int v = orig;
            #pragma unroll
            for (int off = 1; off < 64; off <<= 1) {
                int t = __shfl_up(v, off, 64);
                if (tid >= off) v += t;
            }
            if (i < NBK) scanb[i] = run + v - orig;
            run += __shfl(v, 63, 64);
        }
    }
    __syncthreads();

    // reserve global ranges; convert hist into staging cursor
    for (int i = tid; i < NBK; i += 256) {
        gbase[i] = atomicAdd(&bcur[i], hist[i]);
    }
    __syncthreads();
    for (int i = tid; i < NBK; i += 256) hist[i] = scanb[i];
    __syncthreads();

    // stage reordered-by-bucket in LDS
    #pragma unroll
    for (int e = 0; e < TILE / 256; ++e) {
        if (myD[e] >= 0) {
            int b = myD[e] >> BKT_SHIFT;
            int r = atomicAdd(&hist[b], 1);
            stage[r] = make_int2(myS[e], myD[e]);
        }
    }
    __syncthreads();

    // write runs: consecutive i within a bucket -> consecutive global addrs
    for (int i = tid; i < n; i += 256) {
        int2 p = stage[i];
        int b = p.y >> BKT_SHIFT;
        bp[gbase[b] + (i - scanb[b])] = p;
    }
}

// ---------------- bucket-local counting-sort fill ----------------
__global__ void fill2_k(const int2* __restrict__ bp, const int* __restrict__ rs,
                        int* __restrict__ fptr, int* __restrict__ ss,
                        int N, int E, int NBK) {
    int k = blockIdx.x;
    int beg = rs[k << BKT_SHIFT];
    int next = (k + 1) << BKT_SHIFT;
    int end = (next < N) ? rs[next] : E;
    for (int i = beg + threadIdx.x; i < end; i += 256) {
        int2 p = bp[i];
        int pos = atomicAdd(&fptr[p.y], 1);   // 512B-hot counters
        ss[pos] = p.x;                        // writes within ~8KB window
    }
}

// ---------------- y = (z @ W^T) * dinv[n] ----------------
__global__ void gemm_k(const float* __restrict__ z, const float* __restrict__ W,
                       const float* __restrict__ dinv, float* __restrict__ y, int N) {
    __shared__ float Wt[64 * 68];
    __shared__ float zt[16 * 68];
    int tid = threadIdx.x;
    for (int i = tid; i < DD * DD; i += 256) {
        int d = i >> 6, k = i & 63;
        Wt[k * 68 + d] = W[i];
    }
    {
        int zr = blockIdx.x * 16 + (tid >> 4);
        float4 v = (zr < N) ? reinterpret_cast<const float4*>(z)[(size_t)zr * 16 + (tid & 15)]
                            : make_float4(0.f, 0.f, 0.f, 0.f);
        *reinterpret_cast<float4*>(&zt[(tid >> 4) * 68 + (tid & 15) * 4]) = v;
    }
    __syncthreads();
    int r = tid >> 4;
    int c = tid & 15;
    int row = blockIdx.x * 16 + r;
    float4 acc = make_float4(0.f, 0.f, 0.f, 0.f);
    #pragma unroll
    for (int k = 0; k < DD; ++k) {
        float zv = zt[r * 68 + k];
        float4 w = *reinterpret_cast<const float4*>(&Wt[k * 68 + c * 4]);
        acc.x = fmaf(zv, w.x, acc.x);
        acc.y = fmaf(zv, w.y, acc.y);
        acc.z = fmaf(zv, w.z, acc.z);
        acc.w = fmaf(zv, w.w, acc.w);
    }
    if (row < N) {
        float s = dinv[row];
        acc.x *= s; acc.y *= s; acc.z *= s; acc.w *= s;
        reinterpret_cast<float4*>(y)[(size_t)row * 16 + c] = acc;
    }
}

// ---------------- fused pull-gather + self + bias + ReLU ----------------
__global__ void gather_k(const float4* __restrict__ y4, const float* __restrict__ dinv,
                         const int* __restrict__ rs, const int* __restrict__ cnt,
                         const int* __restrict__ ss, const float4* __restrict__ b4,
                         float4* __restrict__ out4, int N) {
    int tid = threadIdx.x;
    int lane = tid & 63;
    int n = blockIdx.x * 4 + (tid >> 6);
    if (n >= N) return;
    int g = lane >> 3;
    int c = lane & 7;
    int beg = rs[n];
    int num = cnt[n];
    float4 a0 = make_float4(0.f, 0.f, 0.f, 0.f);
    float4 a1 = a0;
    if (g == 0) {
        a0 = y4[(size_t)n * 16 + 2 * c];
        a1 = y4[(size_t)n * 16 + 2 * c + 1];
    }
    for (int j = g; j < num; j += 8) {
        int s = ss[beg + j];
        size_t p = (size_t)s * 16 + 2 * c;
        float4 v0 = y4[p];
        float4 v1 = y4[p + 1];
        a0 = f4add(a0, v0);
        a1 = f4add(a1, v1);
    }
    #pragma unroll
    for (int m = 8; m <= 32; m <<= 1) {
        a0.x += __shfl_xor(a0.x, m, 64);
        a0.y += __shfl_xor(a0.y, m, 64);
        a0.z += __shfl_xor(a0.z, m, 64);
        a0.w += __shfl_xor(a0.w, m, 64);
        a1.x += __shfl_xor(a1.x, m, 64);
        a1.y += __shfl_xor(a1.y, m, 64);
        a1.z += __shfl_xor(a1.z, m, 64);
        a1.w += __shfl_xor(a1.w, m, 64);
    }
    if (g == 0) {
        float dn = dinv[n];
        float4 bb0 = b4[2 * c];
        float4 bb1 = b4[2 * c + 1];
        float4 o0, o1;
        o0.x = fmaxf(fmaf(a0.x, dn, bb0.x), 0.f);
        o0.y = fmaxf(fmaf(a0.y, dn, bb0.y), 0.f);
        o0.z = fmaxf(fmaf(a0.z, dn, bb0.z), 0.f);
        o0.w = fmaxf(fmaf(a0.w, dn, bb0.w), 0.f);
        o1.x = fmaxf(fmaf(a1.x, dn, bb1.x), 0.f);
        o1.y = fmaxf(fmaf(a1.y, dn, bb1.y), 0.f);
        o1.z = fmaxf(fmaf(a1.z, dn, bb1.z), 0.f);
        o1.w = fmaxf(fmaf(a1.w, dn, bb1.w), 0.f);
        out4[(size_t)n * 16 + 2 * c] = o0;
        out4[(size_t)n * 16 + 2 * c + 1] = o1;
    }
}

// ---------------- launch ----------------

extern "C" void kernel_launch(void* const* d_in, const int* in_sizes, int n_in,
                              void* d_out, int out_size, void* d_ws, size_t ws_size,
                              hipStream_t stream) {
    const float* z = (const float*)d_in[0];
    const int* ei  = (const int*)d_in[1];
    const float* W = (const float*)d_in[2];
    const float* b = (const float*)d_in[3];
    float* out = (float*)d_out;

    const int N = in_sizes[0] / DD;
    const int E = in_sizes[1] / 2;
    const int* src = ei;
    const int* dst = ei + E;

    const int nb  = (N + 255) / 256;
    const int NBK = (N + (1 << BKT_SHIFT) - 1) >> BKT_SHIFT;

    // workspace layout
    float* ws   = (float*)d_ws;
    float* y    = ws;                       // 64N f
    float* dinv = ws + (size_t)64 * N;      // N f
    int*   cnt  = (int*)(dinv + N);         // N
    int*   rs   = cnt + N;                  // N
    int*   fptr = rs + N;                   // N
    int*   bsum = fptr + N;                 // nb
    int*   bcur = bsum + nb;                // NBK
    int*   ss   = bcur + NBK;               // E
    int2*  bp   = (int2*)(ss + E);          // E int2 (align 8: offset parity fine — all prior counts even in practice; force align)
    bp = (int2*)((((size_t)bp) + 7) & ~(size_t)7);

    zero_int_k<<<(N + 255) / 256, 256, 0, stream>>>(cnt, N);
    hist_k<<<(E + 255) / 256, 256, 0, stream>>>(dst, cnt, E);
    scan1_k<<<nb, 256, 0, stream>>>(cnt, dinv, rs, bsum, N);
    scan2_k<<<1, 64, 0, stream>>>(bsum, nb);
    scan3_k<<<(N + 255) / 256, 256, 0, stream>>>(rs, bsum, fptr, bcur, N);
    part_k<<<(E + TILE - 1) / TILE, 256, 0, stream>>>(src, dst, bcur, bp, E, NBK);
    fill2_k<<<NBK, 256, 0, stream>>>(bp, rs, fptr, ss, N, E, NBK);
    gemm_k<<<(N + 15) / 16, 256, 0, stream>>>(z, W, dinv, y, N);
    gather_k<<<(N + 3) / 4, 256, 0, stream>>>((const float4*)y, dinv, rs, cnt, ss,
                                              (const float4*)b, (float4*)out, N);
}

// Round 5
// 160.510 us; speedup vs baseline: 3.4889x; 1.5376x over previous
//
#include <hip/hip_runtime.h>

#define DD 64
#define BKT_SHIFT 7                 // 128 nodes per bucket
#define BKT (1 << BKT_SHIFT)
#define TILE 4096                   // edges per partition block
#define MAXBK 1024                  // LDS arrays sized for NBK <= 1024

__device__ __forceinline__ float4 f4add(float4 a, float4 b) {
    return make_float4(a.x + b.x, a.y + b.y, a.z + b.z, a.w + b.w);
}

// ---------------- bucket-count histogram (LDS-aggregated) ----------------
__global__ void zero_k(int* __restrict__ p, int n) {
    int i = blockIdx.x * blockDim.x + threadIdx.x;
    if (i < n) p[i] = 0;
}

__global__ void bhist_k(const int* __restrict__ dst, int* __restrict__ bcnt,
                        int E, int NBK) {
    __shared__ int h[MAXBK];
    int tid = threadIdx.x;
    for (int i = tid; i < NBK; i += 256) h[i] = 0;
    __syncthreads();
    for (int i = blockIdx.x * 256 + tid; i < E; i += gridDim.x * 256)
        atomicAdd(&h[dst[i] >> BKT_SHIFT], 1);
    __syncthreads();
    for (int i = tid; i < NBK; i += 256)
        if (h[i]) atomicAdd(&bcnt[i], h[i]);
}

// one-block exclusive scan of bucket counts -> bbase[0..NBK], copy to bcur
__global__ void bscan_k(const int* __restrict__ bcnt, int* __restrict__ bbase,
                        int* __restrict__ bcur, int NBK) {
    int lane = threadIdx.x;  // 64 threads
    int run = 0;
    for (int base = 0; base < NBK; base += 64) {
        int i = base + lane;
        int orig = (i < NBK) ? bcnt[i] : 0;
        int v = orig;
        #pragma unroll
        for (int off = 1; off < 64; off <<= 1) {
            int t = __shfl_up(v, off, 64);
            if (lane >= off) v += t;
        }
        if (i < NBK) {
            int ex = run + v - orig;
            bbase[i] = ex;
            bcur[i] = ex;
        }
        run += __shfl(v, 63, 64);
    }
    if (lane == 0) bbase[NBK] = run;   // == E
}

// ---------------- bucketed partition: packed edges grouped by dst bucket ----------------
// packed = (src << BKT_SHIFT) | (dst & (BKT-1));  requires N < 2^(31-BKT_SHIFT)
__global__ __launch_bounds__(256) void part_k(const int* __restrict__ src,
                                              const int* __restrict__ dst,
                                              int* __restrict__ bcur,
                                              int* __restrict__ bp,
                                              int E, int NBK) {
    __shared__ int hist[MAXBK];
    __shared__ int scanb[MAXBK];
    __shared__ int gbase[MAXBK];
    __shared__ int stage[TILE];            // 16 KB packed
    __shared__ unsigned short bstage[TILE]; // 8 KB bucket ids

    int tid = threadIdx.x;
    int tbase = blockIdx.x * TILE;
    int n = E - tbase;
    if (n > TILE) n = TILE;

    for (int i = tid; i < NBK; i += 256) hist[i] = 0;
    __syncthreads();

    int pv[TILE / 256];
    int pb[TILE / 256];
    #pragma unroll
    for (int e = 0; e < TILE / 256; ++e) {
        int i = tid + e * 256;
        pb[e] = -1;
        if (i < n) {
            int s = src[tbase + i];
            int d = dst[tbase + i];
            pv[e] = (s << BKT_SHIFT) | (d & (BKT - 1));
            pb[e] = d >> BKT_SHIFT;
            atomicAdd(&hist[pb[e]], 1);
        }
    }
    __syncthreads();

    // one-wave chunked exclusive scan of hist -> scanb
    if (tid < 64) {
        int run = 0;
        for (int base = 0; base < NBK; base += 64) {
            int i = base + tid;
            int orig = (i < NBK) ? hist[i] : 0;
            int v = orig;
            #pragma unroll
            for (int off = 1; off < 64; off <<= 1) {
                int t = __shfl_up(v, off, 64);
                if (tid >= off) v += t;
            }
            if (i < NBK) scanb[i] = run + v - orig;
            run += __shfl(v, 63, 64);
        }
    }
    __syncthreads();

    // reserve global ranges per bucket
    for (int i = tid; i < NBK; i += 256)
        if (hist[i]) gbase[i] = atomicAdd(&bcur[i], hist[i]);
    __syncthreads();
    for (int i = tid; i < NBK; i += 256) hist[i] = scanb[i];  // staging cursor
    __syncthreads();

    #pragma unroll
    for (int e = 0; e < TILE / 256; ++e) {
        if (pb[e] >= 0) {
            int r = atomicAdd(&hist[pb[e]], 1);
            stage[r] = pv[e];
            bstage[r] = (unsigned short)pb[e];
        }
    }
    __syncthreads();

    // contiguous runs per bucket
    for (int i = tid; i < n; i += 256) {
        int b = bstage[i];
        bp[gbase[b] + (i - scanb[b])] = stage[i];
    }
}

// ---------------- per-bucket: node hist + scan + dinv + rs + counting-sort fill ----------------
__global__ void bucket_k(const int* __restrict__ bp, const int* __restrict__ bbase,
                         int* __restrict__ rs, float* __restrict__ dinv,
                         int* __restrict__ ss, int N, int E, int NBK) {
    __shared__ int cnt128[BKT];
    __shared__ int excl[BKT];
    __shared__ int cur[BKT];
    int k = blockIdx.x;
    int ebeg = bbase[k];
    int eend = bbase[k + 1];
    int tid = threadIdx.x;

    if (tid < BKT) cnt128[tid] = 0;
    __syncthreads();
    for (int i = ebeg + tid; i < eend; i += 256)
        atomicAdd(&cnt128[bp[i] & (BKT - 1)], 1);
    __syncthreads();

    // 128-wide LDS ladder scan (inclusive), then convert to exclusive
    if (tid < BKT) excl[tid] = cnt128[tid];
    __syncthreads();
    for (int off = 1; off < BKT; off <<= 1) {
        int t = (tid < BKT && tid >= off) ? excl[tid - off] : 0;
        __syncthreads();
        if (tid < BKT) excl[tid] += t;
        __syncthreads();
    }
    if (tid < BKT) {
        int c = cnt128[tid];
        int ex = excl[tid] - c;
        cur[tid] = ex;
        int node = (k << BKT_SHIFT) + tid;
        if (node < N) {
            rs[node] = ebeg + ex;
            dinv[node] = rsqrtf((float)(1 + c));
        }
    }
    if (k == NBK - 1 && tid == 0) rs[N] = E;
    __syncthreads();

    for (int i = ebeg + tid; i < eend; i += 256) {
        int v = bp[i];
        int l = v & (BKT - 1);
        int pos = atomicAdd(&cur[l], 1);
        ss[ebeg + pos] = v >> BKT_SHIFT;   // src index
    }
}

// ---------------- y = (z @ W^T) * dinv[n] ----------------
__global__ void gemm_k(const float* __restrict__ z, const float* __restrict__ W,
                       const float* __restrict__ dinv, float* __restrict__ y, int N) {
    __shared__ float Wt[64 * 68];
    __shared__ float zt[16 * 68];
    int tid = threadIdx.x;
    for (int i = tid; i < DD * DD; i += 256) {
        int d = i >> 6, k = i & 63;
        Wt[k * 68 + d] = W[i];
    }
    {
        int zr = blockIdx.x * 16 + (tid >> 4);
        float4 v = (zr < N) ? reinterpret_cast<const float4*>(z)[(size_t)zr * 16 + (tid & 15)]
                            : make_float4(0.f, 0.f, 0.f, 0.f);
        *reinterpret_cast<float4*>(&zt[(tid >> 4) * 68 + (tid & 15) * 4]) = v;
    }
    __syncthreads();
    int r = tid >> 4;
    int c = tid & 15;
    int row = blockIdx.x * 16 + r;
    float4 acc = make_float4(0.f, 0.f, 0.f, 0.f);
    #pragma unroll
    for (int k = 0; k < DD; ++k) {
        float zv = zt[r * 68 + k];
        float4 w = *reinterpret_cast<const float4*>(&Wt[k * 68 + c * 4]);
        acc.x = fmaf(zv, w.x, acc.x);
        acc.y = fmaf(zv, w.y, acc.y);
        acc.z = fmaf(zv, w.z, acc.z);
        acc.w = fmaf(zv, w.w, acc.w);
    }
    if (row < N) {
        float s = dinv[row];
        acc.x *= s; acc.y *= s; acc.z *= s; acc.w *= s;
        reinterpret_cast<float4*>(y)[(size_t)row * 16 + c] = acc;
    }
}

// ---------------- fused pull-gather + self + bias + ReLU ----------------
__global__ void gather_k(const float4* __restrict__ y4, const float* __restrict__ dinv,
                         const int* __restrict__ rs, const int* __restrict__ ss,
                         const float4* __restrict__ b4, float4* __restrict__ out4, int N) {
    int tid = threadIdx.x;
    int lane = tid & 63;
    int n = blockIdx.x * 4 + (tid >> 6);
    if (n >= N) return;
    int g = lane >> 3;
    int c = lane & 7;
    int beg = rs[n];
    int num = rs[n + 1] - beg;
    float4 a0 = make_float4(0.f, 0.f, 0.f, 0.f);
    float4 a1 = a0;
    if (g == 0) {
        a0 = y4[(size_t)n * 16 + 2 * c];
        a1 = y4[(size_t)n * 16 + 2 * c + 1];
    }
    for (int j = g; j < num; j += 8) {
        int s = ss[beg + j];
        size_t p = (size_t)s * 16 + 2 * c;
        float4 v0 = y4[p];
        float4 v1 = y4[p + 1];
        a0 = f4add(a0, v0);
        a1 = f4add(a1, v1);
    }
    #pragma unroll
    for (int m = 8; m <= 32; m <<= 1) {
        a0.x += __shfl_xor(a0.x, m, 64);
        a0.y += __shfl_xor(a0.y, m, 64);
        a0.z += __shfl_xor(a0.z, m, 64);
        a0.w += __shfl_xor(a0.w, m, 64);
        a1.x += __shfl_xor(a1.x, m, 64);
        a1.y += __shfl_xor(a1.y, m, 64);
        a1.z += __shfl_xor(a1.z, m, 64);
        a1.w += __shfl_xor(a1.w, m, 64);
    }
    if (g == 0) {
        float dn = dinv[n];
        float4 bb0 = b4[2 * c];
        float4 bb1 = b4[2 * c + 1];
        float4 o0, o1;
        o0.x = fmaxf(fmaf(a0.x, dn, bb0.x), 0.f);
        o0.y = fmaxf(fmaf(a0.y, dn, bb0.y), 0.f);
        o0.z = fmaxf(fmaf(a0.z, dn, bb0.z), 0.f);
        o0.w = fmaxf(fmaf(a0.w, dn, bb0.w), 0.f);
        o1.x = fmaxf(fmaf(a1.x, dn, bb1.x), 0.f);
        o1.y = fmaxf(fmaf(a1.y, dn, bb1.y), 0.f);
        o1.z = fmaxf(fmaf(a1.z, dn, bb1.z), 0.f);
        o1.w = fmaxf(fmaf(a1.w, dn, bb1.w), 0.f);
        out4[(size_t)n * 16 + 2 * c] = o0;
        out4[(size_t)n * 16 + 2 * c + 1] = o1;
    }
}

// ---------------- launch ----------------

extern "C" void kernel_launch(void* const* d_in, const int* in_sizes, int n_in,
                              void* d_out, int out_size, void* d_ws, size_t ws_size,
                              hipStream_t stream) {
    const float* z = (const float*)d_in[0];
    const int* ei  = (const int*)d_in[1];
    const float* W = (const float*)d_in[2];
    const float* b = (const float*)d_in[3];
    float* out = (float*)d_out;

    const int N = in_sizes[0] / DD;
    const int E = in_sizes[1] / 2;
    const int* src = ei;
    const int* dst = ei + E;

    const int NBK = (N + BKT - 1) >> BKT_SHIFT;

    // workspace layout (all 4B-aligned)
    float* ws    = (float*)d_ws;
    float* y     = ws;                        // 64N f
    float* dinv  = ws + (size_t)64 * N;       // N f
    int*   rs    = (int*)(dinv + N);          // N+1
    int*   bcnt  = rs + N + 1;                // NBK
    int*   bbase = bcnt + NBK;                // NBK+1
    int*   bcur  = bbase + NBK + 1;           // NBK
    int*   ss    = bcur + NBK;                // E
    int*   bp    = ss + E;                    // E

    zero_k<<<(NBK + 255) / 256, 256, 0, stream>>>(bcnt, NBK);
    bhist_k<<<256, 256, 0, stream>>>(dst, bcnt, E, NBK);
    bscan_k<<<1, 64, 0, stream>>>(bcnt, bbase, bcur, NBK);
    part_k<<<(E + TILE - 1) / TILE, 256, 0, stream>>>(src, dst, bcur, bp, E, NBK);
    bucket_k<<<NBK, 256, 0, stream>>>(bp, bbase, rs, dinv, ss, N, E, NBK);
    gemm_k<<<(N + 15) / 16, 256, 0, stream>>>(z, W, dinv, y, N);
    gather_k<<<(N + 3) / 4, 256, 0, stream>>>((const float4*)y, dinv, rs, ss,
                                              (const float4*)b, (float4*)out, N);
}

// Round 6
// 142.811 us; speedup vs baseline: 3.9213x; 1.1239x over previous
//
#include <hip/hip_runtime.h>

#define DD 64
#define BKT_SHIFT 7                 // 128 nodes per bucket
#define BKT (1 << BKT_SHIFT)
#define TILE 4096                   // edges per partition block
#define MAXBK 1024                  // LDS arrays sized for NBK <= 1024

__device__ __forceinline__ float bflo(unsigned int u) {
    return __uint_as_float(u << 16);
}
__device__ __forceinline__ float bfhi(unsigned int u) {
    return __uint_as_float(u & 0xffff0000u);
}
__device__ __forceinline__ unsigned short f2bf(float f) {   // RNE
    unsigned int b = __float_as_uint(f);
    return (unsigned short)((b + 0x7fffu + ((b >> 16) & 1u)) >> 16);
}

// ---------------- bucket-count histogram (LDS-aggregated) ----------------
__global__ void zero_k(int* __restrict__ p, int n) {
    int i = blockIdx.x * blockDim.x + threadIdx.x;
    if (i < n) p[i] = 0;
}

__global__ void bhist_k(const int* __restrict__ dst, int* __restrict__ bcnt,
                        int E, int NBK) {
    __shared__ int h[MAXBK];
    int tid = threadIdx.x;
    for (int i = tid; i < NBK; i += 256) h[i] = 0;
    __syncthreads();
    for (int i = blockIdx.x * 256 + tid; i < E; i += gridDim.x * 256)
        atomicAdd(&h[dst[i] >> BKT_SHIFT], 1);
    __syncthreads();
    for (int i = tid; i < NBK; i += 256)
        if (h[i]) atomicAdd(&bcnt[i], h[i]);
}

// one-block exclusive scan of bucket counts -> bbase[0..NBK], copy to bcur
__global__ void bscan_k(const int* __restrict__ bcnt, int* __restrict__ bbase,
                        int* __restrict__ bcur, int NBK) {
    int lane = threadIdx.x;  // 64 threads
    int run = 0;
    for (int base = 0; base < NBK; base += 64) {
        int i = base + lane;
        int orig = (i < NBK) ? bcnt[i] : 0;
        int v = orig;
        #pragma unroll
        for (int off = 1; off < 64; off <<= 1) {
            int t = __shfl_up(v, off, 64);
            if (lane >= off) v += t;
        }
        if (i < NBK) {
            int ex = run + v - orig;
            bbase[i] = ex;
            bcur[i] = ex;
        }
        run += __shfl(v, 63, 64);
    }
    if (lane == 0) bbase[NBK] = run;   // == E
}

// ---------------- bucketed partition: packed edges grouped by dst bucket ----------------
// packed = (src << BKT_SHIFT) | (dst & (BKT-1));  requires N < 2^(31-BKT_SHIFT)
__global__ __launch_bounds__(256) void part_k(const int* __restrict__ src,
                                              const int* __restrict__ dst,
                                              int* __restrict__ bcur,
                                              int* __restrict__ bp,
                                              int E, int NBK) {
    __shared__ int hist[MAXBK];
    __shared__ int scanb[MAXBK];
    __shared__ int gbase[MAXBK];
    __shared__ int stage[TILE];             // 16 KB packed
    __shared__ unsigned short bstage[TILE]; // 8 KB bucket ids

    int tid = threadIdx.x;
    int tbase = blockIdx.x * TILE;
    int n = E - tbase;
    if (n > TILE) n = TILE;

    for (int i = tid; i < NBK; i += 256) hist[i] = 0;
    __syncthreads();

    int pv[TILE / 256];
    int pb[TILE / 256];
    #pragma unroll
    for (int e = 0; e < TILE / 256; ++e) {
        int i = tid + e * 256;
        pb[e] = -1;
        if (i < n) {
            int s = src[tbase + i];
            int d = dst[tbase + i];
            pv[e] = (s << BKT_SHIFT) | (d & (BKT - 1));
            pb[e] = d >> BKT_SHIFT;
            atomicAdd(&hist[pb[e]], 1);
        }
    }
    __syncthreads();

    // one-wave chunked exclusive scan of hist -> scanb
    if (tid < 64) {
        int run = 0;
        for (int base = 0; base < NBK; base += 64) {
            int i = base + tid;
            int orig = (i < NBK) ? hist[i] : 0;
            int v = orig;
            #pragma unroll
            for (int off = 1; off < 64; off <<= 1) {
                int t = __shfl_up(v, off, 64);
                if (tid >= off) v += t;
            }
            if (i < NBK) scanb[i] = run + v - orig;
            run += __shfl(v, 63, 64);
        }
    }
    __syncthreads();

    // reserve global ranges per bucket
    for (int i = tid; i < NBK; i += 256)
        if (hist[i]) gbase[i] = atomicAdd(&bcur[i], hist[i]);
    __syncthreads();
    for (int i = tid; i < NBK; i += 256) hist[i] = scanb[i];  // staging cursor
    __syncthreads();

    #pragma unroll
    for (int e = 0; e < TILE / 256; ++e) {
        if (pb[e] >= 0) {
            int r = atomicAdd(&hist[pb[e]], 1);
            stage[r] = pv[e];
            bstage[r] = (unsigned short)pb[e];
        }
    }
    __syncthreads();

    // contiguous runs per bucket
    for (int i = tid; i < n; i += 256) {
        int b = bstage[i];
        bp[gbase[b] + (i - scanb[b])] = stage[i];
    }
}

// ---------------- per-bucket: node hist + scan + dinv + rs + counting-sort fill ----------------
__global__ void bucket_k(const int* __restrict__ bp, const int* __restrict__ bbase,
                         int* __restrict__ rs, float* __restrict__ dinv,
                         int* __restrict__ ss, int N, int E, int NBK) {
    __shared__ int cnt128[BKT];
    __shared__ int excl[BKT];
    __shared__ int cur[BKT];
    int k = blockIdx.x;
    int ebeg = bbase[k];
    int eend = bbase[k + 1];
    int tid = threadIdx.x;

    if (tid < BKT) cnt128[tid] = 0;
    __syncthreads();
    for (int i = ebeg + tid; i < eend; i += 256)
        atomicAdd(&cnt128[bp[i] & (BKT - 1)], 1);
    __syncthreads();

    if (tid < BKT) excl[tid] = cnt128[tid];
    __syncthreads();
    for (int off = 1; off < BKT; off <<= 1) {
        int t = (tid < BKT && tid >= off) ? excl[tid - off] : 0;
        __syncthreads();
        if (tid < BKT) excl[tid] += t;
        __syncthreads();
    }
    if (tid < BKT) {
        int c = cnt128[tid];
        int ex = excl[tid] - c;
        cur[tid] = ex;
        int node = (k << BKT_SHIFT) + tid;
        if (node < N) {
            rs[node] = ebeg + ex;
            dinv[node] = rsqrtf((float)(1 + c));
        }
    }
    if (k == NBK - 1 && tid == 0) rs[N] = E;
    __syncthreads();

    for (int i = ebeg + tid; i < eend; i += 256) {
        int v = bp[i];
        int l = v & (BKT - 1);
        int pos = atomicAdd(&cur[l], 1);
        ss[ebeg + pos] = v >> BKT_SHIFT;   // src index
    }
}

// ---------------- y = bf16( (z @ W^T) * dinv[n] ) ----------------
__global__ void gemm_k(const float* __restrict__ z, const float* __restrict__ W,
                       const float* __restrict__ dinv, ushort4* __restrict__ ybf,
                       int N) {
    __shared__ float Wt[64 * 68];
    __shared__ float zt[16 * 68];
    int tid = threadIdx.x;
    for (int i = tid; i < DD * DD; i += 256) {
        int d = i >> 6, k = i & 63;
        Wt[k * 68 + d] = W[i];
    }
    {
        int zr = blockIdx.x * 16 + (tid >> 4);
        float4 v = (zr < N) ? reinterpret_cast<const float4*>(z)[(size_t)zr * 16 + (tid & 15)]
                            : make_float4(0.f, 0.f, 0.f, 0.f);
        *reinterpret_cast<float4*>(&zt[(tid >> 4) * 68 + (tid & 15) * 4]) = v;
    }
    __syncthreads();
    int r = tid >> 4;
    int c = tid & 15;
    int row = blockIdx.x * 16 + r;
    float4 acc = make_float4(0.f, 0.f, 0.f, 0.f);
    #pragma unroll
    for (int k = 0; k < DD; ++k) {
        float zv = zt[r * 68 + k];
        float4 w = *reinterpret_cast<const float4*>(&Wt[k * 68 + c * 4]);
        acc.x = fmaf(zv, w.x, acc.x);
        acc.y = fmaf(zv, w.y, acc.y);
        acc.z = fmaf(zv, w.z, acc.z);
        acc.w = fmaf(zv, w.w, acc.w);
    }
    if (row < N) {
        float s = dinv[row];
        ushort4 o;
        o.x = f2bf(acc.x * s);
        o.y = f2bf(acc.y * s);
        o.z = f2bf(acc.z * s);
        o.w = f2bf(acc.w * s);
        ybf[(size_t)row * 16 + c] = o;   // cols 4c..4c+3
    }
}

// ---------------- fused pull-gather (bf16 rows) + self + bias + ReLU ----------------
// wave per node; 8 edge-groups x 8 lanes; lane owns 8 cols = one uint4 (ushort8).
__global__ void gather_k(const uint4* __restrict__ ybf, const float* __restrict__ dinv,
                         const int* __restrict__ rs, const int* __restrict__ ss,
                         const float4* __restrict__ b4, float4* __restrict__ out4, int N) {
    int tid = threadIdx.x;
    int lane = tid & 63;
    int n = blockIdx.x * 4 + (tid >> 6);
    if (n >= N) return;
    int g = lane >> 3;          // edge group 0..7
    int c = lane & 7;           // col block: 8 bf16 cols = 16 B
    int beg = rs[n];
    int num = rs[n + 1] - beg;
    float4 a0 = make_float4(0.f, 0.f, 0.f, 0.f);
    float4 a1 = a0;
    if (g == 0) {               // self-loop message
        uint4 v = ybf[(size_t)n * 8 + c];
        a0.x = bflo(v.x); a0.y = bfhi(v.x); a0.z = bflo(v.y); a0.w = bfhi(v.y);
        a1.x = bflo(v.z); a1.y = bfhi(v.z); a1.z = bflo(v.w); a1.w = bfhi(v.w);
    }
    for (int j = g; j < num; j += 8) {
        int s = ss[beg + j];                 // uniform within 8-lane group
        uint4 v = ybf[(size_t)s * 8 + c];    // 128B row per edge across the group
        a0.x += bflo(v.x); a0.y += bfhi(v.x);
        a0.z += bflo(v.y); a0.w += bfhi(v.y);
        a1.x += bflo(v.z); a1.y += bfhi(v.z);
        a1.z += bflo(v.w); a1.w += bfhi(v.w);
    }
    // reduce across the 8 groups (same c): masks 8,16,32
    #pragma unroll
    for (int m = 8; m <= 32; m <<= 1) {
        a0.x += __shfl_xor(a0.x, m, 64);
        a0.y += __shfl_xor(a0.y, m, 64);
        a0.z += __shfl_xor(a0.z, m, 64);
        a0.w += __shfl_xor(a0.w, m, 64);
        a1.x += __shfl_xor(a1.x, m, 64);
        a1.y += __shfl_xor(a1.y, m, 64);
        a1.z += __shfl_xor(a1.z, m, 64);
        a1.w += __shfl_xor(a1.w, m, 64);
    }
    if (g == 0) {
        float dn = dinv[n];
        float4 bb0 = b4[2 * c];
        float4 bb1 = b4[2 * c + 1];
        float4 o0, o1;
        o0.x = fmaxf(fmaf(a0.x, dn, bb0.x), 0.f);
        o0.y = fmaxf(fmaf(a0.y, dn, bb0.y), 0.f);
        o0.z = fmaxf(fmaf(a0.z, dn, bb0.z), 0.f);
        o0.w = fmaxf(fmaf(a0.w, dn, bb0.w), 0.f);
        o1.x = fmaxf(fmaf(a1.x, dn, bb1.x), 0.f);
        o1.y = fmaxf(fmaf(a1.y, dn, bb1.y), 0.f);
        o1.z = fmaxf(fmaf(a1.z, dn, bb1.z), 0.f);
        o1.w = fmaxf(fmaf(a1.w, dn, bb1.w), 0.f);
        out4[(size_t)n * 16 + 2 * c] = o0;
        out4[(size_t)n * 16 + 2 * c + 1] = o1;
    }
}

// ---------------- launch ----------------

extern "C" void kernel_launch(void* const* d_in, const int* in_sizes, int n_in,
                              void* d_out, int out_size, void* d_ws, size_t ws_size,
                              hipStream_t stream) {
    const float* z = (const float*)d_in[0];
    const int* ei  = (const int*)d_in[1];
    const float* W = (const float*)d_in[2];
    const float* b = (const float*)d_in[3];
    float* out = (float*)d_out;

    const int N = in_sizes[0] / DD;
    const int E = in_sizes[1] / 2;
    const int* src = ei;
    const int* dst = ei + E;

    const int NBK = (N + BKT - 1) >> BKT_SHIFT;

    // workspace layout
    unsigned short* ybf = (unsigned short*)d_ws;      // 64N ushorts (bf16)
    float* dinv  = (float*)(ybf + (size_t)64 * N);    // N f
    int*   rs    = (int*)(dinv + N);                  // N+1
    int*   bcnt  = rs + N + 1;                        // NBK
    int*   bbase = bcnt + NBK;                        // NBK+1
    int*   bcur  = bbase + NBK + 1;                   // NBK
    int*   ss    = bcur + NBK;                        // E
    int*   bp    = ss + E;                            // E

    zero_k<<<(NBK + 255) / 256, 256, 0, stream>>>(bcnt, NBK);
    bhist_k<<<256, 256, 0, stream>>>(dst, bcnt, E, NBK);
    bscan_k<<<1, 64, 0, stream>>>(bcnt, bbase, bcur, NBK);
    part_k<<<(E + TILE - 1) / TILE, 256, 0, stream>>>(src, dst, bcur, bp, E, NBK);
    bucket_k<<<NBK, 256, 0, stream>>>(bp, bbase, rs, dinv, ss, N, E, NBK);
    gemm_k<<<(N + 15) / 16, 256, 0, stream>>>(z, W, dinv, (ushort4*)ybf, N);
    gather_k<<<(N + 3) / 4, 256, 0, stream>>>((const uint4*)ybf, dinv, rs, ss,
                                              (const float4*)b, (float4*)out, N);
}